// Round 7
// baseline (653.096 us; speedup 1.0000x reference)
//
#include <hip/hip_runtime.h>
#include <hip/hip_bf16.h>

typedef unsigned int uint;
typedef unsigned short ushort;
typedef float v2f __attribute__((ext_vector_type(2)));

#define NATOMS 20000
#define NEDGES 640000
#define FD 128
#define F3 384
#define NR 20
#define MAPB 16     // atoms per block, MLP
#define GAPB 8      // atoms per block, gather

__device__ __forceinline__ uint f2bfu(float f) {   // f32 -> bf16 bits, RNE
  const uint u = __float_as_uint(f);
  return (u + 0x7FFFu + ((u >> 16) & 1u)) >> 16;
}
__device__ __forceinline__ float bf2f(ushort u) { return __uint_as_float((uint)u << 16); }

// ---------------------------------------------------------------------------
// CSR build: histogram -> exclusive scan.
// ---------------------------------------------------------------------------
__global__ __launch_bounds__(256) void hist_kernel(const int* __restrict__ eidx,
                                                   int* __restrict__ cnt) {
  const int e = blockIdx.x * 256 + threadIdx.x;
  if (e < NEDGES) atomicAdd(&cnt[eidx[e]], 1);
}

__global__ __launch_bounds__(512) void scan_kernel(const int* __restrict__ cnt,
                                                   int* __restrict__ off) {
  __shared__ int part[512];
  const int t = threadIdx.x;
  const int CH = (NATOMS + 511) / 512;
  const int base = t * CH;
  int s = 0;
  for (int k = 0; k < CH; ++k) {
    const int idx = base + k;
    if (idx < NATOMS) s += cnt[idx];
  }
  part[t] = s;
  __syncthreads();
  if (t == 0) {
    int run = 0;
    for (int i = 0; i < 512; ++i) { const int tmp = part[i]; part[i] = run; run += tmp; }
    off[NATOMS] = run;
  }
  __syncthreads();
  int run = part[t];
  for (int k = 0; k < CH; ++k) {
    const int idx = base + k;
    if (idx < NATOMS) { off[idx] = run; run += cnt[idx]; }
  }
}

// ---------------------------------------------------------------------------
// Prep: 32B record at destination-sorted position.
// rec dwords: [0] v0=sin(th)*env/d  [1] 2cos(th)  [2] env  [3..5] dir  [6] j  [7] pad
// Basis sin((r+1)th)*env/d regenerated in gather via linear recurrence from v0,2c.
// ---------------------------------------------------------------------------
__global__ __launch_bounds__(256) void prep_kernel(
    const int* __restrict__ eidx, const float* __restrict__ ew,
    int* __restrict__ cursor, uint4* __restrict__ basisS)
{
  const int e = blockIdx.x * 256 + threadIdx.x;
  if (e >= NEDGES) return;
  const int i = eidx[e];
  const int j = eidx[NEDGES + e];
  const int pos = atomicAdd(&cursor[i], 1);

  const float w0 = ew[(size_t)e * 3 + 0];
  const float w1 = ew[(size_t)e * 3 + 1];
  const float w2 = ew[(size_t)e * 3 + 2];
  const float d = sqrtf(w0 * w0 + w1 * w1 + w2 * w2);
  const float invd = 1.f / d;
  float s1, c1;
  __sincosf(d * 0.628318530717958f, &s1, &c1);   // theta = pi*d/5
  const float env = (d < 5.f) ? 0.5f * (c1 + 1.f) : 0.f;

  uint4 r0, r1;
  r0.x = __float_as_uint(s1 * env * invd);
  r0.y = __float_as_uint(2.f * c1);
  r0.z = __float_as_uint(env);
  r0.w = __float_as_uint(w0 * invd);
  r1.x = __float_as_uint(w1 * invd);
  r1.y = __float_as_uint(w2 * invd);
  r1.z = (uint)j;
  r1.w = 0u;
  basisS[(size_t)pos * 2 + 0] = r0;
  basisS[(size_t)pos * 2 + 1] = r1;
}

// ---------------------------------------------------------------------------
// Phase 1: x = silu(q@W1+b1)@W2+b2 -> bf16 into xm[:,0:384]; mu cast -> xm[:,384:768].
// xm row (per atom): 384 bf16 x | 384 bf16 mu  (1536 B contiguous gather target)
// ---------------------------------------------------------------------------
__global__ __launch_bounds__(128) void mlp_kernel(
    const float* __restrict__ q, const float* __restrict__ mu,
    const float* __restrict__ W1, const float* __restrict__ b1,
    const float* __restrict__ W2, const float* __restrict__ b2v,
    ushort* __restrict__ xm)
{
  __shared__ float qL[MAPB][FD];
  __shared__ float hL[MAPB][FD];
  const int t = threadIdx.x;
  const int a0 = blockIdx.x * MAPB;

  #pragma unroll
  for (int a = 0; a < MAPB; ++a) qL[a][t] = q[(size_t)(a0 + a) * FD + t];
  __syncthreads();

  float hacc[MAPB];
  const float bb1 = b1[t];
  #pragma unroll
  for (int a = 0; a < MAPB; ++a) hacc[a] = bb1;
  for (int i = 0; i < FD; ++i) {
    const float w = W1[(size_t)i * FD + t];
    #pragma unroll
    for (int a = 0; a < MAPB; ++a) hacc[a] += qL[a][i] * w;
  }
  #pragma unroll
  for (int a = 0; a < MAPB; ++a) hL[a][t] = hacc[a] / (1.f + __expf(-hacc[a]));
  __syncthreads();

  float x0[MAPB], x1[MAPB], x2[MAPB];
  const float c0 = b2v[t], c1 = b2v[FD + t], c2 = b2v[2 * FD + t];
  #pragma unroll
  for (int a = 0; a < MAPB; ++a) { x0[a] = c0; x1[a] = c1; x2[a] = c2; }
  for (int i = 0; i < FD; ++i) {
    const float w0 = W2[(size_t)i * F3 + t];
    const float w1 = W2[(size_t)i * F3 + FD + t];
    const float w2 = W2[(size_t)i * F3 + 2 * FD + t];
    #pragma unroll
    for (int a = 0; a < MAPB; ++a) {
      const float hv = hL[a][i];
      x0[a] += hv * w0; x1[a] += hv * w1; x2[a] += hv * w2;
    }
  }
  #pragma unroll
  for (int a = 0; a < MAPB; ++a) {
    ushort* xa = xm + (size_t)(a0 + a) * 768;
    xa[t]           = (ushort)f2bfu(x0[a]);
    xa[128 + t]     = (ushort)f2bfu(x1[a]);
    xa[256 + t]     = (ushort)f2bfu(x2[a]);
  }
  // mu -> bf16 alongside x
  #pragma unroll
  for (int a = 0; a < MAPB; ++a) {
    const float* ma = mu + (size_t)(a0 + a) * F3;
    ushort* xa = xm + (size_t)(a0 + a) * 768 + 384;
    for (int r = t; r < F3; r += 128) xa[r] = (ushort)f2bfu(ma[r]);
  }
}

// ---------------------------------------------------------------------------
// Phase 2: persistent 128-thread blocks, GAPB atoms each (contiguous CSR range).
// 64-edge chunks: stage 32B recs (stride-1) -> unpack to f32 LDS (1 thread/edge
// runs the 20-step recurrence) -> compute. Thread t owns column t of all 3
// channels (30 v2f Wf regs -> pk_fma); no cross-wave combine, no per-atom sync.
// x/mu gathers 4-deep pipelined from the packed xm rows.
// ---------------------------------------------------------------------------
__global__ __launch_bounds__(128) void gather_kernel(
    const float* __restrict__ q, const float* __restrict__ mu,
    const ushort* __restrict__ xm,
    const float* __restrict__ Wf, const float* __restrict__ bfv,
    const int* __restrict__ off, const uint* __restrict__ basisS,
    float* __restrict__ out)
{
  __shared__ uint stage[64 * 8];     // 2 KB raw records
  __shared__ float fb[64][28];       // 7 KB: [0..19] basis f32, [20] env, [21..23] dir, [24] j-bits
  const int t = threadIdx.x;
  const int a0 = blockIdx.x * GAPB;

  v2f wf0[10], wf1[10], wf2[10];
  #pragma unroll
  for (int r = 0; r < 10; ++r) {
    wf0[r] = (v2f){Wf[(size_t)(2 * r) * F3 + t],       Wf[(size_t)(2 * r + 1) * F3 + t]};
    wf1[r] = (v2f){Wf[(size_t)(2 * r) * F3 + 128 + t], Wf[(size_t)(2 * r + 1) * F3 + 128 + t]};
    wf2[r] = (v2f){Wf[(size_t)(2 * r) * F3 + 256 + t], Wf[(size_t)(2 * r + 1) * F3 + 256 + t]};
  }
  const float bias0 = bfv[t], bias1 = bfv[128 + t], bias2 = bfv[256 + t];

  int a = a0;
  const int beg  = off[a0];
  const int pEnd = off[a0 + GAPB];
  int nxt = off[a + 1];
  float acq = 0.f, ac0 = 0.f, ac1 = 0.f, ac2 = 0.f;
  const size_t NQ = (size_t)NATOMS * FD;

  for (int cb = beg; cb < pEnd; cb += 64) {
    const int nn = min(64, pEnd - cb);
    __syncthreads();
    if (t < nn * 2) ((uint4*)stage)[t] = ((const uint4*)basisS)[(size_t)cb * 2 + t];
    __syncthreads();
    if (t < nn) {
      const uint4 r0 = ((const uint4*)stage)[t * 2];
      const uint4 r1 = ((const uint4*)stage)[t * 2 + 1];
      fb[t][20] = __uint_as_float(r0.z);
      fb[t][21] = __uint_as_float(r0.w);
      fb[t][22] = __uint_as_float(r1.x);
      fb[t][23] = __uint_as_float(r1.y);
      fb[t][24] = __uint_as_float(r1.z);           // j bits
      float vp = 0.f, vc = __uint_as_float(r0.x);
      const float tc = __uint_as_float(r0.y);
      #pragma unroll
      for (int r = 0; r < NR; ++r) { fb[t][r] = vc; const float vn = tc * vc - vp; vp = vc; vc = vn; }
    }
    __syncthreads();

    // 4-deep gather pipeline from packed xm rows
    ushort pxq[4], pxr[4], pxm[4], pm0[4], pm1[4], pm2[4];
    #pragma unroll
    for (int d = 0; d < 4; ++d) if (d < nn) {
      const uint jj = __float_as_uint(fb[d][24]);
      const ushort* xp = xm + (size_t)jj * 768;
      pxq[d] = xp[t];       pxr[d] = xp[128 + t]; pxm[d] = xp[256 + t];
      pm0[d] = xp[384 + t]; pm1[d] = xp[512 + t]; pm2[d] = xp[640 + t];
    }

    for (int k = 0; k < nn; ++k) {
      const int g = cb + k;
      while (g == nxt) {                      // flush completed atom(s) — block-uniform
        out[(size_t)a * FD + t] = q[(size_t)a * FD + t] + acq;
        const size_t mi = (size_t)a * F3;
        out[NQ + mi + t]       = mu[mi + t]       + ac0;
        out[NQ + mi + 128 + t] = mu[mi + 128 + t] + ac1;
        out[NQ + mi + 256 + t] = mu[mi + 256 + t] + ac2;
        acq = ac0 = ac1 = ac2 = 0.f;
        ++a; nxt = off[a + 1];
      }
      const int d = k & 3;
      const float* fk = fb[k];
      const float4* f4 = (const float4*)fk;    // uniform-broadcast b128 reads
      const float4 B0 = f4[0], B1 = f4[1], B2 = f4[2], B3 = f4[3], B4 = f4[4];
      const float4 M  = f4[5];                 // env, dir0, dir1, dir2
      v2f bb[10];
      bb[0] = (v2f){B0.x, B0.y}; bb[1] = (v2f){B0.z, B0.w};
      bb[2] = (v2f){B1.x, B1.y}; bb[3] = (v2f){B1.z, B1.w};
      bb[4] = (v2f){B2.x, B2.y}; bb[5] = (v2f){B2.z, B2.w};
      bb[6] = (v2f){B3.x, B3.y}; bb[7] = (v2f){B3.z, B3.w};
      bb[8] = (v2f){B4.x, B4.y}; bb[9] = (v2f){B4.z, B4.w};

      v2f s0 = (v2f){0.f, 0.f}, s1 = (v2f){0.f, 0.f}, s2 = (v2f){0.f, 0.f};
      #pragma unroll
      for (int r = 0; r < 10; ++r) {
        s0 += bb[r] * wf0[r];
        s1 += bb[r] * wf1[r];
        s2 += bb[r] * wf2[r];
      }
      const float env = M.x;
      const float f0 = s0.x + s0.y + env * bias0;
      const float f1 = s1.x + s1.y + env * bias1;
      const float f2 = s2.x + s2.y + env * bias2;

      acq += f0 * bf2f(pxq[d]);
      const float dmuR = f1 * bf2f(pxr[d]);
      const float dmm  = f2 * bf2f(pxm[d]);
      ac0 += dmuR * M.y + dmm * bf2f(pm0[d]);
      ac1 += dmuR * M.z + dmm * bf2f(pm1[d]);
      ac2 += dmuR * M.w + dmm * bf2f(pm2[d]);

      const int kd = k + 4;
      if (kd < nn) {                           // refill slot d with edge k+4
        const uint jj = __float_as_uint(fb[kd][24]);
        const ushort* xp = xm + (size_t)jj * 768;
        pxq[d] = xp[t];       pxr[d] = xp[128 + t]; pxm[d] = xp[256 + t];
        pm0[d] = xp[384 + t]; pm1[d] = xp[512 + t]; pm2[d] = xp[640 + t];
      }
    }
  }
  // flush remaining atoms (incl. boundary-at-pEnd and zero-edge tails)
  while (a < a0 + GAPB) {
    out[(size_t)a * FD + t] = q[(size_t)a * FD + t] + acq;
    const size_t mi = (size_t)a * F3;
    out[NQ + mi + t]       = mu[mi + t]       + ac0;
    out[NQ + mi + 128 + t] = mu[mi + 128 + t] + ac1;
    out[NQ + mi + 256 + t] = mu[mi + 256 + t] + ac2;
    acq = ac0 = ac1 = ac2 = 0.f;
    ++a;
  }
}

extern "C" void kernel_launch(void* const* d_in, const int* in_sizes, int n_in,
                              void* d_out, int out_size, void* d_ws, size_t ws_size,
                              hipStream_t stream) {
  const float* q   = (const float*)d_in[0];
  const float* mu  = (const float*)d_in[1];
  const int*   eix = (const int*)d_in[2];
  const float* ew  = (const float*)d_in[3];
  const float* W1  = (const float*)d_in[4];
  const float* b1  = (const float*)d_in[5];
  const float* W2  = (const float*)d_in[6];
  const float* b2v = (const float*)d_in[7];
  const float* Wf  = (const float*)d_in[8];
  const float* bfv = (const float*)d_in[9];
  float* out = (float*)d_out;

  // Workspace (~51.4 MB): [basisS 32B*E | xm bf16 N*768 | off N+1 | cnt N | cursor N]
  char* w = (char*)d_ws;
  uint*   basisS = (uint*)w;    w += (size_t)NEDGES * 32;
  ushort* xm     = (ushort*)w;  w += (size_t)NATOMS * 768 * sizeof(ushort);
  int*    off    = (int*)w;     w += (size_t)(NATOMS + 1) * sizeof(int);
  int*    cnt    = (int*)w;     w += (size_t)NATOMS * sizeof(int);
  int*    cursor = (int*)w;

  hipMemsetAsync(cnt, 0, (size_t)NATOMS * sizeof(int), stream);

  hist_kernel<<<(NEDGES + 255) / 256, 256, 0, stream>>>(eix, cnt);
  scan_kernel<<<1, 512, 0, stream>>>(cnt, off);
  hipMemcpyAsync(cursor, off, (size_t)NATOMS * sizeof(int),
                 hipMemcpyDeviceToDevice, stream);
  prep_kernel<<<(NEDGES + 255) / 256, 256, 0, stream>>>(eix, ew, cursor,
                                                        (uint4*)basisS);

  mlp_kernel<<<NATOMS / MAPB, 128, 0, stream>>>(q, mu, W1, b1, W2, b2v, xm);

  gather_kernel<<<NATOMS / GAPB, 128, 0, stream>>>(q, mu, xm, Wf, bfv,
                                                   off, basisS, out);
}

// Round 8
// 601.130 us; speedup vs baseline: 1.0864x; 1.0864x over previous
//
#include <hip/hip_runtime.h>
#include <hip/hip_bf16.h>

typedef unsigned int uint;
typedef unsigned short ushort;
typedef float v2f __attribute__((ext_vector_type(2)));

#define NATOMS 20000
#define NEDGES 640000
#define FD 128
#define F3 384
#define NR 20
#define MAPB 16     // atoms per block, MLP
#define GAPB 2      // atoms per block, gather (small -> 10000 blocks -> occupancy)

__device__ __forceinline__ uint f2bfu(float f) {   // f32 -> bf16 bits, RNE
  const uint u = __float_as_uint(f);
  return (u + 0x7FFFu + ((u >> 16) & 1u)) >> 16;
}
__device__ __forceinline__ float bflo(uint u) { return __uint_as_float(u << 16); }
__device__ __forceinline__ float bfhi(uint u) { return __uint_as_float(u & 0xFFFF0000u); }

// ---------------------------------------------------------------------------
// CSR build: histogram -> exclusive scan (writes off AND cursor).
// ---------------------------------------------------------------------------
__global__ __launch_bounds__(256) void hist_kernel(const int* __restrict__ eidx,
                                                   int* __restrict__ cnt) {
  const int e = blockIdx.x * 256 + threadIdx.x;
  if (e < NEDGES) atomicAdd(&cnt[eidx[e]], 1);
}

__global__ __launch_bounds__(512) void scan_kernel(const int* __restrict__ cnt,
                                                   int* __restrict__ off,
                                                   int* __restrict__ cursor) {
  __shared__ int part[512];
  const int t = threadIdx.x;
  const int CH = (NATOMS + 511) / 512;
  const int base = t * CH;
  int s = 0;
  for (int k = 0; k < CH; ++k) {
    const int idx = base + k;
    if (idx < NATOMS) s += cnt[idx];
  }
  part[t] = s;
  __syncthreads();
  if (t == 0) {
    int run = 0;
    for (int i = 0; i < 512; ++i) { const int tmp = part[i]; part[i] = run; run += tmp; }
    off[NATOMS] = run;
  }
  __syncthreads();
  int run = part[t];
  for (int k = 0; k < CH; ++k) {
    const int idx = base + k;
    if (idx < NATOMS) { off[idx] = run; cursor[idx] = run; run += cnt[idx]; }
  }
}

// ---------------------------------------------------------------------------
// Prep: 32B record at destination-sorted position.
// rec: [0] v0=sin(th)*env/d  [1] 2cos(th)  [2] env  [3..5] dir  [6] j  [7] pad
// ---------------------------------------------------------------------------
__global__ __launch_bounds__(256) void prep_kernel(
    const int* __restrict__ eidx, const float* __restrict__ ew,
    int* __restrict__ cursor, uint4* __restrict__ basisS)
{
  const int e = blockIdx.x * 256 + threadIdx.x;
  if (e >= NEDGES) return;
  const int i = eidx[e];
  const int j = eidx[NEDGES + e];
  const int pos = atomicAdd(&cursor[i], 1);

  const float w0 = ew[(size_t)e * 3 + 0];
  const float w1 = ew[(size_t)e * 3 + 1];
  const float w2 = ew[(size_t)e * 3 + 2];
  const float d = sqrtf(w0 * w0 + w1 * w1 + w2 * w2);
  const float invd = 1.f / d;
  float s1, c1;
  __sincosf(d * 0.628318530717958f, &s1, &c1);   // theta = pi*d/5
  const float env = (d < 5.f) ? 0.5f * (c1 + 1.f) : 0.f;

  uint4 r0, r1;
  r0.x = __float_as_uint(s1 * env * invd);
  r0.y = __float_as_uint(2.f * c1);
  r0.z = __float_as_uint(env);
  r0.w = __float_as_uint(w0 * invd);
  r1.x = __float_as_uint(w1 * invd);
  r1.y = __float_as_uint(w2 * invd);
  r1.z = (uint)j;
  r1.w = 0u;
  basisS[(size_t)pos * 2 + 0] = r0;
  basisS[(size_t)pos * 2 + 1] = r1;
}

// ---------------------------------------------------------------------------
// Phase 1: x = silu(q@W1+b1)@W2+b2; pack per (atom,feature t) a 12B record
// [x0|x1, x2|m0, m1|m2] (bf16 pairs) -> gather reads ONE dwordx3 per edge.
// ---------------------------------------------------------------------------
__global__ __launch_bounds__(128) void mlp_kernel(
    const float* __restrict__ q, const float* __restrict__ mu,
    const float* __restrict__ W1, const float* __restrict__ b1,
    const float* __restrict__ W2, const float* __restrict__ b2v,
    uint* __restrict__ xmp)
{
  __shared__ float qL[MAPB][FD];
  __shared__ float hL[MAPB][FD];
  const int t = threadIdx.x;
  const int a0 = blockIdx.x * MAPB;

  #pragma unroll
  for (int a = 0; a < MAPB; ++a) qL[a][t] = q[(size_t)(a0 + a) * FD + t];
  __syncthreads();

  float hacc[MAPB];
  const float bb1 = b1[t];
  #pragma unroll
  for (int a = 0; a < MAPB; ++a) hacc[a] = bb1;
  for (int i = 0; i < FD; ++i) {
    const float w = W1[(size_t)i * FD + t];
    #pragma unroll
    for (int a = 0; a < MAPB; ++a) hacc[a] += qL[a][i] * w;
  }
  #pragma unroll
  for (int a = 0; a < MAPB; ++a) hL[a][t] = hacc[a] / (1.f + __expf(-hacc[a]));
  __syncthreads();

  float x0[MAPB], x1[MAPB], x2[MAPB];
  const float c0 = b2v[t], c1 = b2v[FD + t], c2 = b2v[2 * FD + t];
  #pragma unroll
  for (int a = 0; a < MAPB; ++a) { x0[a] = c0; x1[a] = c1; x2[a] = c2; }
  for (int i = 0; i < FD; ++i) {
    const float w0 = W2[(size_t)i * F3 + t];
    const float w1 = W2[(size_t)i * F3 + FD + t];
    const float w2 = W2[(size_t)i * F3 + 2 * FD + t];
    #pragma unroll
    for (int a = 0; a < MAPB; ++a) {
      const float hv = hL[a][i];
      x0[a] += hv * w0; x1[a] += hv * w1; x2[a] += hv * w2;
    }
  }
  #pragma unroll
  for (int a = 0; a < MAPB; ++a) {
    const int n = a0 + a;
    const float* ma = mu + (size_t)n * F3;
    const float m0 = ma[t], m1 = ma[FD + t], m2 = ma[2 * FD + t];
    uint* dst = xmp + ((size_t)n * FD + t) * 3;
    dst[0] = f2bfu(x0[a]) | (f2bfu(x1[a]) << 16);
    dst[1] = f2bfu(x2[a]) | (f2bfu(m0) << 16);
    dst[2] = f2bfu(m1)    | (f2bfu(m2) << 16);
  }
}

// ---------------------------------------------------------------------------
// Phase 2: 128-thread blocks, GAPB=2 atoms each (contiguous CSR range).
// Thread t owns filter columns {t, 128+t, 256+t}. Basis regenerated once per
// edge into f32 LDS; inner loop reads it as v2f broadcasts (LDS pipe, not
// VALU). One dwordx3 gather per edge, 4-deep pipelined.
// ---------------------------------------------------------------------------
__global__ __launch_bounds__(128) void gather_kernel(
    const float* __restrict__ q, const float* __restrict__ mu,
    const uint* __restrict__ xmp,
    const float* __restrict__ Wf, const float* __restrict__ bfv,
    const int* __restrict__ off, const uint* __restrict__ basisS,
    float* __restrict__ out)
{
  __shared__ uint stage[64 * 8];   // raw 32B records
  __shared__ float fb[64][28];     // [0..19] basis f32, [20..23] env+dir, [24] j
  const int t = threadIdx.x;
  const int a0 = blockIdx.x * GAPB;

  v2f wf0[10], wf1[10], wf2[10];
  #pragma unroll
  for (int r = 0; r < 10; ++r) {
    wf0[r] = (v2f){Wf[(size_t)(2 * r) * F3 + t],       Wf[(size_t)(2 * r + 1) * F3 + t]};
    wf1[r] = (v2f){Wf[(size_t)(2 * r) * F3 + 128 + t], Wf[(size_t)(2 * r + 1) * F3 + 128 + t]};
    wf2[r] = (v2f){Wf[(size_t)(2 * r) * F3 + 256 + t], Wf[(size_t)(2 * r + 1) * F3 + 256 + t]};
  }
  const float bias0 = bfv[t], bias1 = bfv[128 + t], bias2 = bfv[256 + t];

  int a = a0;
  const int beg  = off[a0];
  const int pEnd = off[a0 + GAPB];
  int nxt = off[a + 1];
  float acq = 0.f, ac0 = 0.f, ac1 = 0.f, ac2 = 0.f;
  const size_t NQ = (size_t)NATOMS * FD;

  for (int cb = beg; cb < pEnd; cb += 64) {
    const int nn = min(64, pEnd - cb);
    __syncthreads();
    if (t < nn * 2) ((uint4*)stage)[t] = ((const uint4*)basisS)[(size_t)cb * 2 + t];
    __syncthreads();
    if (t < nn) {
      const uint4 r0 = ((const uint4*)stage)[t * 2];
      const uint4 r1 = ((const uint4*)stage)[t * 2 + 1];
      fb[t][20] = __uint_as_float(r0.z);
      fb[t][21] = __uint_as_float(r0.w);
      fb[t][22] = __uint_as_float(r1.x);
      fb[t][23] = __uint_as_float(r1.y);
      fb[t][24] = __uint_as_float(r1.z);           // j bits
      float vp = 0.f, vc = __uint_as_float(r0.x);
      const float tc = __uint_as_float(r0.y);
      #pragma unroll
      for (int r = 0; r < NR; ++r) { fb[t][r] = vc; const float vn = tc * vc - vp; vp = vc; vc = vn; }
    }
    __syncthreads();

    uint p0[4], p1[4], p2[4];                      // 4-deep dwordx3 pipeline
    #pragma unroll
    for (int d = 0; d < 4; ++d) if (d < nn) {
      const uint jj = __float_as_uint(fb[d][24]);
      const uint* xp = xmp + ((size_t)jj * FD + t) * 3;
      p0[d] = xp[0]; p1[d] = xp[1]; p2[d] = xp[2];
    }

    for (int k = 0; k < nn; ++k) {
      const int g = cb + k;
      while (g == nxt) {                           // block-uniform flush
        out[(size_t)a * FD + t] = q[(size_t)a * FD + t] + acq;
        const size_t mi = (size_t)a * F3;
        out[NQ + mi + t]       = mu[mi + t]       + ac0;
        out[NQ + mi + 128 + t] = mu[mi + 128 + t] + ac1;
        out[NQ + mi + 256 + t] = mu[mi + 256 + t] + ac2;
        acq = ac0 = ac1 = ac2 = 0.f;
        ++a; nxt = off[a + 1];
      }
      const int d = k & 3;
      const float* fk = fb[k];
      const v2f* b2 = (const v2f*)fk;              // 10x ds_read_b64 broadcast
      const float4 M = *(const float4*)(fk + 20);  // env, dir0..2

      v2f s0 = (v2f){0.f, 0.f}, s1 = (v2f){0.f, 0.f}, s2 = (v2f){0.f, 0.f};
      #pragma unroll
      for (int r = 0; r < 10; ++r) {
        const v2f bb = b2[r];
        s0 += bb * wf0[r];
        s1 += bb * wf1[r];
        s2 += bb * wf2[r];
      }
      const float env = M.x;
      const float f0 = s0.x + s0.y + env * bias0;
      const float f1 = s1.x + s1.y + env * bias1;
      const float f2 = s2.x + s2.y + env * bias2;

      acq += f0 * bflo(p0[d]);
      const float dmuR = f1 * bfhi(p0[d]);
      const float dmm  = f2 * bflo(p1[d]);
      ac0 += dmuR * M.y + dmm * bfhi(p1[d]);
      ac1 += dmuR * M.z + dmm * bflo(p2[d]);
      ac2 += dmuR * M.w + dmm * bfhi(p2[d]);

      const int kd = k + 4;
      if (kd < nn) {
        const uint jj = __float_as_uint(fb[kd][24]);
        const uint* xp = xmp + ((size_t)jj * FD + t) * 3;
        p0[d] = xp[0]; p1[d] = xp[1]; p2[d] = xp[2];
      }
    }
  }
  while (a < a0 + GAPB) {                          // tail / zero-edge atoms
    out[(size_t)a * FD + t] = q[(size_t)a * FD + t] + acq;
    const size_t mi = (size_t)a * F3;
    out[NQ + mi + t]       = mu[mi + t]       + ac0;
    out[NQ + mi + 128 + t] = mu[mi + 128 + t] + ac1;
    out[NQ + mi + 256 + t] = mu[mi + 256 + t] + ac2;
    acq = ac0 = ac1 = ac2 = 0.f;
    ++a;
  }
}

extern "C" void kernel_launch(void* const* d_in, const int* in_sizes, int n_in,
                              void* d_out, int out_size, void* d_ws, size_t ws_size,
                              hipStream_t stream) {
  const float* q   = (const float*)d_in[0];
  const float* mu  = (const float*)d_in[1];
  const int*   eix = (const int*)d_in[2];
  const float* ew  = (const float*)d_in[3];
  const float* W1  = (const float*)d_in[4];
  const float* b1  = (const float*)d_in[5];
  const float* W2  = (const float*)d_in[6];
  const float* b2v = (const float*)d_in[7];
  const float* Wf  = (const float*)d_in[8];
  const float* bfv = (const float*)d_in[9];
  float* out = (float*)d_out;

  // Workspace (~51.4 MB): [basisS 32B*E | xmp 12B*N*128 | off N+1 | cnt N | cursor N]
  char* w = (char*)d_ws;
  uint* basisS = (uint*)w;  w += (size_t)NEDGES * 32;
  uint* xmp    = (uint*)w;  w += (size_t)NATOMS * FD * 3 * sizeof(uint);
  int*  off    = (int*)w;   w += (size_t)(NATOMS + 1) * sizeof(int);
  int*  cnt    = (int*)w;   w += (size_t)NATOMS * sizeof(int);
  int*  cursor = (int*)w;

  hipMemsetAsync(cnt, 0, (size_t)NATOMS * sizeof(int), stream);

  hist_kernel<<<(NEDGES + 255) / 256, 256, 0, stream>>>(eix, cnt);
  scan_kernel<<<1, 512, 0, stream>>>(cnt, off, cursor);
  prep_kernel<<<(NEDGES + 255) / 256, 256, 0, stream>>>(eix, ew, cursor,
                                                        (uint4*)basisS);

  mlp_kernel<<<NATOMS / MAPB, 128, 0, stream>>>(q, mu, W1, b1, W2, b2v, xmp);

  gather_kernel<<<NATOMS / GAPB, 128, 0, stream>>>(q, mu, xmp, Wf, bfv,
                                                   off, basisS, out);
}